// Round 13
// baseline (248.848 us; speedup 1.0000x reference)
//
#include <hip/hip_runtime.h>

// confidence_maps: (8,6,4,512,512) f32; warp_masks: (8,1,512,512) f32;
// gauss_kernel: (1,1,5,5) f32.
// Output: mask (48,1,512,512) f32 + rate scalar = 12,582,913 floats.
//
// Validated invariants (rounds 1-12, absmax 0.0 x12):
//  - rate == 0.5 exactly; ego rows (l==0) all-ones, excluded from rate.
//  - max_c(sigmoid) == sigmoid(max_c); separable gaussian factorization.
//  - 20-bit keys are exact integer surrogates: decided bits provably match
//    the f64 reference outside a +/-KAPPA=3 key band (kappa*q = 2.9e-6 >=
//    4*eps_f32); band resolved by exact-f64 (branchy m_val, 25-tap) rank
//    with (value desc, index asc) tie-break.
//
// Round-13 (access-pattern rewrite of conv; R10-12 evidence: pipeline moves
// bytes at only ~2.7 TB/s, conv latency-bound at 1.85 TB/s with per-pixel
// halo branches + div/mod addressing + x-halo re-reads):
//  - conv512: 512-thread blocks, one column/thread, 32-row segments; m in an
//    8-row circular LDS buffer; branchless hconv (LDS +-2); rolling 5-reg
//    vconv; register prefetch of next row before the single per-row barrier;
//    wave-uniform row-bound branches only; all global reads coalesced.
//  - hist2 pass DELETED: single-level 4096-bin hist (k>>8) fused into conv;
//    gather marks decided bits vs bin-level cuts and gathers the whole
//    cutoff bin (+/-3 keys); resolve finds the exact 20-bit k* by integer
//    rank over C~800 candidate keys (O(C^2) int, cheap), then f64-resolves
//    only |key-k*|<=3 (~25). Same band proof, pstar -> k* computed in-kernel.
//  - 4 kernels total: ego, conv512, gather, resolve.

#define NROWSEL 40
#define NPIX    262144
#define KSEL    131072
#define CAND_CAP 4096
#define UCAP    1024
#define KAPPA   3

// ---- workspace layout (bytes) ----
#define OFF_KEY 0ull                   // 40*262144 u32 = 41,943,040
#define OFF_H1  41943040ull            // 40*4096 u32   =    655,360
#define OFF_ST  42598400ull            // 40*2 int      =        320
#define OFF_CC  42598720ull            // 40 u32        =        160
#define OFF_CI  42598880ull            // 40*4096 int   =    655,360
#define OFF_CK  43254240ull            // 40*4096 u32   =    655,360
#define META_U32 163960                // (H1+ST+CC)/4 = 655,840 B

// exact f64 m (identical formula rounds 1-12); used only in resolve.
__device__ __forceinline__ double m_val(const float* __restrict__ confr,
                                        const float* __restrict__ warpr,
                                        int gy, int gx) {
  if (gy < 0 || gy >= 512 || gx < 0 || gx >= 512) return 0.0;
  int off = gy * 512 + gx;
  float x0 = confr[off];
  float x1 = confr[NPIX + off];
  float x2 = confr[2 * NPIX + off];
  float x3 = confr[3 * NPIX + off];
  float mx = fmaxf(fmaxf(x0, x1), fmaxf(x2, x3));
  double s = 1.0 / (1.0 + exp(-(double)mx));
  return s * (double)warpr[off];
}

// K0: fill the 8 ego rows (l==0) with 1.0 AND zero selection metadata.
__global__ void ego_fill_kernel(float* __restrict__ out,
                                unsigned* __restrict__ meta) {
  int i = blockIdx.x * 256 + threadIdx.x;   // 524288 float4 units
  int b = i >> 16;
  int o4 = i & 65535;
  float4* p = (float4*)(out + (size_t)b * 6u * NPIX) + o4;
  *p = make_float4(1.f, 1.f, 1.f, 1.f);
  if (i < META_U32) meta[i] = 0u;
}

// K1: 512-wide row-streaming fused m + separable conv + 20-bit key store +
// 4096-bin histogram (k>>8). 512 thr/block, 32-row output segments.
// LDS: 8x512 f32 circular m + 4096 u32 hist ~= 32.8 KB -> 4 blocks/CU.
__global__ __launch_bounds__(512) void conv_kernel(
    const float* __restrict__ conf, const float* __restrict__ warp,
    const float* __restrict__ gk, unsigned* __restrict__ keys,
    unsigned* __restrict__ hist1) {
  const int blk = blockIdx.x;        // 40 * 16
  const int j = blk >> 4;            // image 0..39
  const int y0 = (blk & 15) << 5;    // output rows y0..y0+31
  const int b = j / 5;
  const int l = j % 5 + 1;
  const float* confr = conf + (size_t)(b * 6 + l) * 4u * NPIX;
  const float* warpr = warp + (size_t)b * NPIX;

  __shared__ float mrow[8][512];     // 16384 B circular buffer
  __shared__ unsigned lh[4096];      // 16384 B histogram
  __shared__ float wr5[5], wc5[5];
  const int x = threadIdx.x;         // column
  if (x < 5) {
    wr5[x] = gk[10 + x];                 // c * a_dx  (middle row)
    wc5[x] = gk[x * 5 + 2] / gk[12];     // a_dy      (middle col / center)
  }
  for (int i = x; i < 4096; i += 512) lh[i] = 0u;

  // m for row y, column x, in registers (wave-uniform row bound only).
  auto mload = [&](int y) -> float {
    float v = 0.f;
    if (y >= 0 && y < 512) {
      int off = y * 512 + x;
      float a0 = confr[off];
      float a1 = confr[NPIX + off];
      float a2 = confr[2 * NPIX + off];
      float a3 = confr[3 * NPIX + off];
      float mx = fmaxf(fmaxf(a0, a1), fmaxf(a2, a3));
      v = warpr[off] / (1.0f + expf(-mx));
    }
    return v;
  };
  // horizontal 5-tap from LDS row (y&7), branchless edge zeros.
  auto hconv = [&](int y) -> float {
    const float* r = mrow[y & 7];
    int xm2 = x >= 2 ? x - 2 : 0;
    int xm1 = x >= 1 ? x - 1 : 0;
    int xp1 = x <= 510 ? x + 1 : 511;
    int xp2 = x <= 509 ? x + 2 : 511;
    float v0 = x >= 2 ? r[xm2] : 0.f;
    float v1 = x >= 1 ? r[xm1] : 0.f;
    float v3 = x <= 510 ? r[xp1] : 0.f;
    float v4 = x <= 509 ? r[xp2] : 0.f;
    float a = v0 * wr5[0];
    a = fmaf(wr5[1], v1, a);
    a = fmaf(wr5[2], r[x], a);
    a = fmaf(wr5[3], v3, a);
    a = fmaf(wr5[4], v4, a);
    return a;
  };

  // prologue: rows y0-2..y0+1 into LDS, row y0+2 staged in mreg.
  float mreg = mload(y0 - 2);
  for (int r = 0; r < 4; ++r) {
    mrow[(y0 - 2 + r) & 7][x] = mreg;
    mreg = mload(y0 - 1 + r);
  }
  __syncthreads();
  float h0 = hconv(y0 - 2);
  float h1 = hconv(y0 - 1);
  float h2 = hconv(y0);
  float h3 = hconv(y0 + 1);

  unsigned* keyrow = keys + (size_t)j * NPIX;
#pragma unroll 1
  for (int yy = y0; yy < y0 + 32; ++yy) {
    mrow[(yy + 2) & 7][x] = mreg;          // write row yy+2 (slot unused)
    if (yy < y0 + 31) mreg = mload(yy + 3);// prefetch overlaps barrier+math
    __syncthreads();                        // row yy+2 visible
    float h4 = hconv(yy + 2);
    float acc = h0 * wc5[0];
    acc = fmaf(wc5[1], h1, acc);
    acc = fmaf(wc5[2], h2, acc);
    acc = fmaf(wc5[3], h3, acc);
    acc = fmaf(wc5[4], h4, acc);
    unsigned k = (unsigned)fminf(fmaxf(acc * 1048576.0f, 0.0f), 1048575.0f);
    keyrow[yy * 512 + x] = k;
    atomicAdd(&lh[k >> 8], 1u);
    h0 = h1; h1 = h2; h2 = h3; h3 = h4;
  }
  __syncthreads();
  for (int i = x; i < 4096; i += 512)
    if (lh[i]) atomicAdd(&hist1[j * 4096 + i], lh[i]);
}

// K2: inline 4096-bin scan -> cutoff bin b1, A1 = exact count above bin;
// write decided mask bits (key > hi_cut); gather bin+band candidates.
__global__ __launch_bounds__(256) void mask_gather_kernel(
    const unsigned* __restrict__ keys, const unsigned* __restrict__ hist1,
    float* __restrict__ out, int* __restrict__ st,
    unsigned* __restrict__ ccount, int* __restrict__ cidx,
    unsigned* __restrict__ ckey) {
  int blk = blockIdx.x;              // 40 * 32
  int j = blk >> 5, seg = blk & 31;  // 8192 keys per segment
  int b = j / 5, l = j % 5 + 1;
  int rowg = b * 6 + l;
  __shared__ unsigned hs[4096];
  __shared__ unsigned red[256];
  __shared__ int s_b1;
  int tid = threadIdx.x;
  for (int i = tid; i < 4096; i += 256) hs[i] = hist1[j * 4096 + i];
  __syncthreads();
  unsigned s = 0;
#pragma unroll 4
  for (int k = 0; k < 16; ++k) s += hs[tid * 16 + k];
  red[tid] = s;
  __syncthreads();
  if (tid == 0) {
    unsigned cum = 0; int b1 = 0; unsigned A1 = 0;
    for (int c = 255; c >= 0; --c) {
      if (cum + red[c] >= (unsigned)KSEL) {
        unsigned cc2 = cum;
        for (int k = 15; k >= 0; --k) {
          unsigned hv = hs[c * 16 + k];
          if (cc2 + hv >= (unsigned)KSEL) { b1 = c * 16 + k; A1 = cc2; break; }
          cc2 += hv;
        }
        break;
      }
      cum += red[c];
    }
    s_b1 = b1;
    if (seg == 0) { st[j * 2] = b1; st[j * 2 + 1] = (int)A1; }
  }
  __syncthreads();
  int lo_cut = (s_b1 << 8) - KAPPA;         // candidates: [lo_cut, hi_cut]
  int hi_cut = ((s_b1 + 1) << 8) + KAPPA;   // decided IN: key > hi_cut

  const uint4* kp = (const uint4*)(keys + (size_t)j * NPIX + seg * 8192);
  float4* o4 = (float4*)(out + (size_t)rowg * NPIX + seg * 8192);
#pragma unroll
  for (int it = 0; it < 8; ++it) {
    int q = tid + it * 256;
    uint4 k4 = kp[q];
    unsigned w[4] = {k4.x, k4.y, k4.z, k4.w};
    float4 mv;
    float* mf = (float*)&mv;
#pragma unroll
    for (int e = 0; e < 4; ++e) {
      int k = (int)w[e];
      mf[e] = k > hi_cut ? 1.f : 0.f;
      if (k >= lo_cut && k <= hi_cut) {
        unsigned sl = atomicAdd(&ccount[j], 1u);
        if (sl < CAND_CAP) {
          cidx[j * CAND_CAP + sl] = seg * 8192 + q * 4 + e;
          ckey[j * CAND_CAP + sl] = (unsigned)k;
        }
      }
    }
    o4[q] = mv;
  }
}

// K3: in-kernel fine cutoff. T = #winners among candidates; k* = T-th
// largest candidate key (integer O(C^2) rank); keys > k*+3 decided IN;
// |key-k*|<=3 resolved by exact f64 + (value desc, index asc) rank.
__global__ __launch_bounds__(256) void resolve_kernel(
    const float* __restrict__ conf, const float* __restrict__ warp,
    const float* __restrict__ gk, const int* __restrict__ st,
    const unsigned* __restrict__ ccount, const int* __restrict__ cidx,
    const unsigned* __restrict__ ckey, float* __restrict__ out) {
  int j = blockIdx.x;                // 40
  int b = j / 5, l = j % 5 + 1;
  int rowg = b * 6 + l;
  const float* confr = conf + (size_t)rowg * 4u * NPIX;
  const float* warpr = warp + (size_t)b * NPIX;
  __shared__ unsigned kk[CAND_CAP];  // 16 KB
  __shared__ int ii[CAND_CAP];       // 16 KB
  __shared__ double uvs[UCAP];       //  8 KB
  __shared__ int uid[UCAP];          //  4 KB
  __shared__ unsigned red[256];
  __shared__ double g[25];
  __shared__ unsigned s_kstar, s_ucnt;
  int tid = threadIdx.x;
  if (tid < 25) g[tid] = (double)gk[tid];
  if (tid == 0) { s_kstar = 0xFFFFFFFFu; s_ucnt = 0u; }
  int b1 = st[j * 2];
  int A1 = st[j * 2 + 1];
  int C = (int)min(ccount[j], (unsigned)CAND_CAP);
  unsigned binTop = ((unsigned)(b1 + 1)) << 8;   // keys >= binTop are in A1
  unsigned cntHi = 0;
  for (int i = tid; i < C; i += 256) {
    kk[i] = ckey[j * CAND_CAP + i];
    ii[i] = cidx[j * CAND_CAP + i];
    cntHi += kk[i] >= binTop ? 1u : 0u;
  }
  red[tid] = cntHi;
  __syncthreads();
  for (int sft = 128; sft > 0; sft >>= 1) {
    if (tid < sft) red[tid] += red[tid + sft];
    __syncthreads();
  }
  int T = KSEL - A1 + (int)red[0];   // winners among candidates
  __syncthreads();
  // k* = min key with #{> key} < T  (the T-th largest candidate key)
  for (int i = tid; i < C; i += 256) {
    unsigned ki = kk[i];
    int gt = 0;
    for (int q = 0; q < C; ++q) gt += kk[q] > ki ? 1 : 0;
    if (gt < T) atomicMin(&s_kstar, ki);
  }
  __syncthreads();
  unsigned kstar = s_kstar;
  // decided IN (key > k*+3); collect uncertain (|key-k*| <= 3); count D
  unsigned dc = 0;
  for (int i = tid; i < C; i += 256) {
    int d = (int)kk[i] - (int)kstar;
    if (d > KAPPA) {
      out[(size_t)rowg * NPIX + ii[i]] = 1.0f;
      dc++;
    } else if (d >= -KAPPA) {
      unsigned u = atomicAdd(&s_ucnt, 1u);
      if (u < UCAP) uid[u] = ii[i];
    }
  }
  red[tid] = dc;
  __syncthreads();
  for (int sft = 128; sft > 0; sft >>= 1) {
    if (tid < sft) red[tid] += red[tid + sft];
    __syncthreads();
  }
  int need = T - (int)red[0];
  int U = (int)min(s_ucnt, (unsigned)UCAP);
  // exact f64 eval of uncertain (identical formula to rounds 1-12)
  for (int u = tid; u < U; u += 256) {
    int idx = uid[u];
    int y = idx >> 9, xx = idx & 511;
    double acc = 0.0;
#pragma unroll
    for (int dy = 0; dy < 5; ++dy)
#pragma unroll
      for (int dx = 0; dx < 5; ++dx)
        acc = fma(g[dy * 5 + dx], m_val(confr, warpr, y + dy - 2, xx + dx - 2), acc);
    uvs[u] = acc;
  }
  __syncthreads();
  for (int u = tid; u < U; u += 256) {
    double v = uvs[u];
    int id = uid[u];
    int r = 0;
    for (int q = 0; q < U; ++q) {
      double vq = uvs[q];
      r += (vq > v) || (vq == v && uid[q] < id) ? 1 : 0;
    }
    if (r < need) out[(size_t)rowg * NPIX + id] = 1.0f;
  }
  if (j == 0 && tid == 0) out[12582912] = 0.5f;  // rate == 0.5 exactly
}

extern "C" void kernel_launch(void* const* d_in, const int* in_sizes, int n_in,
                              void* d_out, int out_size, void* d_ws, size_t ws_size,
                              hipStream_t stream) {
  const float* conf = (const float*)d_in[0];
  const float* warp = (const float*)d_in[1];
  const float* gk   = (const float*)d_in[2];
  float* out = (float*)d_out;
  char* ws = (char*)d_ws;

  unsigned* keys = (unsigned*)(ws + OFF_KEY);
  unsigned* h1   = (unsigned*)(ws + OFF_H1);
  int*      st   = (int*)(ws + OFF_ST);
  unsigned* cc   = (unsigned*)(ws + OFF_CC);
  int*      ci   = (int*)(ws + OFF_CI);
  unsigned* ck   = (unsigned*)(ws + OFF_CK);

  // 4 kernels. No hipMemsetAsync.
  ego_fill_kernel<<<2048, 256, 0, stream>>>(out, h1);
  conv_kernel<<<NROWSEL * 16, 512, 0, stream>>>(conf, warp, gk, keys, h1);
  mask_gather_kernel<<<NROWSEL * 32, 256, 0, stream>>>(keys, h1, out, st, cc, ci, ck);
  resolve_kernel<<<NROWSEL, 256, 0, stream>>>(conf, warp, gk, st, cc, ci, ck, out);
}

// Round 14
// 132.583 us; speedup vs baseline: 1.8769x; 1.8769x over previous
//
#include <hip/hip_runtime.h>

// confidence_maps: (8,6,4,512,512) f32; warp_masks: (8,1,512,512) f32;
// gauss_kernel: (1,1,5,5) f32.
// Output: mask (48,1,512,512) f32 + rate scalar = 12,582,913 floats.
//
// Validated invariants (rounds 1-13, absmax 0.0 x13):
//  - rate == 0.5 exactly; ego rows (l==0) all-ones, excluded from rate.
//  - max_c(sigmoid) == sigmoid(max_c); separable gaussian factorization.
//  - 20-bit keys are exact integer surrogates: decided bits provably match
//    the f64 reference outside a +/-KAPPA=3 key band; band resolved by
//    exact-f64 (branchy m_val, 25-tap) rank with (value desc, index asc).
//  - R13 resolve: T = K - A1 + #(cand >= binTop); k* = T-th largest cand
//    key (int rank); f64-resolve only |key-k*|<=3.
//
// Round-14 (fix the gather atomic serialization; R13 profile: gather =
// 151.7us, VALUBusy 1.9%, 0.44 TB/s — C~850 same-address global atomicAdds
// per row at ~150ns each = ~130us):
//  - gather now aggregates candidates in an LDS stack (LDS atomics), then
//    ONE global atomicAdd per block reserves a range in cidx/ckey, then a
//    coalesced LDS->global copy. Same-address global atomics: 850 -> 32/row.
//  - conv512 / resolve / ego unchanged (R13-proven).

#define NROWSEL 40
#define NPIX    262144
#define KSEL    131072
#define CAND_CAP 4096
#define LCAP    2048
#define UCAP    1024
#define KAPPA   3

// ---- workspace layout (bytes) ----
#define OFF_KEY 0ull                   // 40*262144 u32 = 41,943,040
#define OFF_H1  41943040ull            // 40*4096 u32   =    655,360
#define OFF_ST  42598400ull            // 40*2 int      =        320
#define OFF_CC  42598720ull            // 40 u32        =        160
#define OFF_CI  42598880ull            // 40*4096 int   =    655,360
#define OFF_CK  43254240ull            // 40*4096 u32   =    655,360
#define META_U32 163960                // (H1+ST+CC)/4 = 655,840 B

// exact f64 m (identical formula rounds 1-13); used only in resolve.
__device__ __forceinline__ double m_val(const float* __restrict__ confr,
                                        const float* __restrict__ warpr,
                                        int gy, int gx) {
  if (gy < 0 || gy >= 512 || gx < 0 || gx >= 512) return 0.0;
  int off = gy * 512 + gx;
  float x0 = confr[off];
  float x1 = confr[NPIX + off];
  float x2 = confr[2 * NPIX + off];
  float x3 = confr[3 * NPIX + off];
  float mx = fmaxf(fmaxf(x0, x1), fmaxf(x2, x3));
  double s = 1.0 / (1.0 + exp(-(double)mx));
  return s * (double)warpr[off];
}

// K0: fill the 8 ego rows (l==0) with 1.0 AND zero selection metadata.
__global__ void ego_fill_kernel(float* __restrict__ out,
                                unsigned* __restrict__ meta) {
  int i = blockIdx.x * 256 + threadIdx.x;   // 524288 float4 units
  int b = i >> 16;
  int o4 = i & 65535;
  float4* p = (float4*)(out + (size_t)b * 6u * NPIX) + o4;
  *p = make_float4(1.f, 1.f, 1.f, 1.f);
  if (i < META_U32) meta[i] = 0u;
}

// K1: 512-wide row-streaming fused m + separable conv + 20-bit key store +
// 4096-bin histogram (k>>8). 512 thr/block, 32-row output segments.
__global__ __launch_bounds__(512) void conv_kernel(
    const float* __restrict__ conf, const float* __restrict__ warp,
    const float* __restrict__ gk, unsigned* __restrict__ keys,
    unsigned* __restrict__ hist1) {
  const int blk = blockIdx.x;        // 40 * 16
  const int j = blk >> 4;            // image 0..39
  const int y0 = (blk & 15) << 5;    // output rows y0..y0+31
  const int b = j / 5;
  const int l = j % 5 + 1;
  const float* confr = conf + (size_t)(b * 6 + l) * 4u * NPIX;
  const float* warpr = warp + (size_t)b * NPIX;

  __shared__ float mrow[8][512];     // 16384 B circular buffer
  __shared__ unsigned lh[4096];      // 16384 B histogram
  __shared__ float wr5[5], wc5[5];
  const int x = threadIdx.x;         // column
  if (x < 5) {
    wr5[x] = gk[10 + x];                 // c * a_dx  (middle row)
    wc5[x] = gk[x * 5 + 2] / gk[12];     // a_dy      (middle col / center)
  }
  for (int i = x; i < 4096; i += 512) lh[i] = 0u;

  auto mload = [&](int y) -> float {
    float v = 0.f;
    if (y >= 0 && y < 512) {
      int off = y * 512 + x;
      float a0 = confr[off];
      float a1 = confr[NPIX + off];
      float a2 = confr[2 * NPIX + off];
      float a3 = confr[3 * NPIX + off];
      float mx = fmaxf(fmaxf(a0, a1), fmaxf(a2, a3));
      v = warpr[off] / (1.0f + expf(-mx));
    }
    return v;
  };
  auto hconv = [&](int y) -> float {
    const float* r = mrow[y & 7];
    int xm2 = x >= 2 ? x - 2 : 0;
    int xm1 = x >= 1 ? x - 1 : 0;
    int xp1 = x <= 510 ? x + 1 : 511;
    int xp2 = x <= 509 ? x + 2 : 511;
    float v0 = x >= 2 ? r[xm2] : 0.f;
    float v1 = x >= 1 ? r[xm1] : 0.f;
    float v3 = x <= 510 ? r[xp1] : 0.f;
    float v4 = x <= 509 ? r[xp2] : 0.f;
    float a = v0 * wr5[0];
    a = fmaf(wr5[1], v1, a);
    a = fmaf(wr5[2], r[x], a);
    a = fmaf(wr5[3], v3, a);
    a = fmaf(wr5[4], v4, a);
    return a;
  };

  float mreg = mload(y0 - 2);
  for (int r = 0; r < 4; ++r) {
    mrow[(y0 - 2 + r) & 7][x] = mreg;
    mreg = mload(y0 - 1 + r);
  }
  __syncthreads();
  float h0 = hconv(y0 - 2);
  float h1 = hconv(y0 - 1);
  float h2 = hconv(y0);
  float h3 = hconv(y0 + 1);

  unsigned* keyrow = keys + (size_t)j * NPIX;
#pragma unroll 1
  for (int yy = y0; yy < y0 + 32; ++yy) {
    mrow[(yy + 2) & 7][x] = mreg;
    if (yy < y0 + 31) mreg = mload(yy + 3);
    __syncthreads();
    float h4 = hconv(yy + 2);
    float acc = h0 * wc5[0];
    acc = fmaf(wc5[1], h1, acc);
    acc = fmaf(wc5[2], h2, acc);
    acc = fmaf(wc5[3], h3, acc);
    acc = fmaf(wc5[4], h4, acc);
    unsigned k = (unsigned)fminf(fmaxf(acc * 1048576.0f, 0.0f), 1048575.0f);
    keyrow[yy * 512 + x] = k;
    atomicAdd(&lh[k >> 8], 1u);
    h0 = h1; h1 = h2; h2 = h3; h3 = h4;
  }
  __syncthreads();
  for (int i = x; i < 4096; i += 512)
    if (lh[i]) atomicAdd(&hist1[j * 4096 + i], lh[i]);
}

// K2: inline 4096-bin scan -> cutoff bin b1, A1; write decided mask bits;
// gather bin+band candidates via LDS stack + ONE global atomic per block.
__global__ __launch_bounds__(256) void mask_gather_kernel(
    const unsigned* __restrict__ keys, const unsigned* __restrict__ hist1,
    float* __restrict__ out, int* __restrict__ st,
    unsigned* __restrict__ ccount, int* __restrict__ cidx,
    unsigned* __restrict__ ckey) {
  int blk = blockIdx.x;              // 40 * 32
  int j = blk >> 5, seg = blk & 31;  // 8192 keys per segment
  int b = j / 5, l = j % 5 + 1;
  int rowg = b * 6 + l;
  __shared__ unsigned hs[4096];      // 16 KB
  __shared__ unsigned red[256];
  __shared__ int lidx[LCAP];         //  8 KB
  __shared__ unsigned lkey[LCAP];    //  8 KB
  __shared__ unsigned s_lcnt, s_base, s_n;
  __shared__ int s_b1;
  int tid = threadIdx.x;
  if (tid == 0) s_lcnt = 0u;
  for (int i = tid; i < 4096; i += 256) hs[i] = hist1[j * 4096 + i];
  __syncthreads();
  unsigned s = 0;
#pragma unroll 4
  for (int k = 0; k < 16; ++k) s += hs[tid * 16 + k];
  red[tid] = s;
  __syncthreads();
  if (tid == 0) {
    unsigned cum = 0; int b1 = 0; unsigned A1 = 0;
    for (int c = 255; c >= 0; --c) {
      if (cum + red[c] >= (unsigned)KSEL) {
        unsigned cc2 = cum;
        for (int k = 15; k >= 0; --k) {
          unsigned hv = hs[c * 16 + k];
          if (cc2 + hv >= (unsigned)KSEL) { b1 = c * 16 + k; A1 = cc2; break; }
          cc2 += hv;
        }
        break;
      }
      cum += red[c];
    }
    s_b1 = b1;
    if (seg == 0) { st[j * 2] = b1; st[j * 2 + 1] = (int)A1; }
  }
  __syncthreads();
  int lo_cut = (s_b1 << 8) - KAPPA;         // candidates: [lo_cut, hi_cut]
  int hi_cut = ((s_b1 + 1) << 8) + KAPPA;   // decided IN: key > hi_cut

  const uint4* kp = (const uint4*)(keys + (size_t)j * NPIX + seg * 8192);
  float4* o4 = (float4*)(out + (size_t)rowg * NPIX + seg * 8192);
#pragma unroll
  for (int it = 0; it < 8; ++it) {
    int q = tid + it * 256;
    uint4 k4 = kp[q];
    unsigned w[4] = {k4.x, k4.y, k4.z, k4.w};
    float4 mv;
    float* mf = (float*)&mv;
#pragma unroll
    for (int e = 0; e < 4; ++e) {
      int k = (int)w[e];
      mf[e] = k > hi_cut ? 1.f : 0.f;
      if (k >= lo_cut && k <= hi_cut) {
        unsigned sl = atomicAdd(&s_lcnt, 1u);       // LDS atomic (fast)
        if (sl < (unsigned)LCAP) {
          lidx[sl] = seg * 8192 + q * 4 + e;
          lkey[sl] = (unsigned)k;
        }
      }
    }
    o4[q] = mv;
  }
  __syncthreads();
  if (tid == 0) {
    unsigned n = min(s_lcnt, (unsigned)LCAP);
    s_n = n;
    s_base = n ? atomicAdd(&ccount[j], n) : 0u;     // ONE global atomic
  }
  __syncthreads();
  unsigned n = s_n, base = s_base;
  for (unsigned i = tid; i < n; i += 256) {
    unsigned d = base + i;
    if (d < (unsigned)CAND_CAP) {
      cidx[j * CAND_CAP + d] = lidx[i];
      ckey[j * CAND_CAP + d] = lkey[i];
    }
  }
}

// K3: in-kernel fine cutoff (R13-proven). T = #winners among candidates;
// k* = T-th largest candidate key; keys > k*+3 decided IN; |key-k*|<=3
// resolved by exact f64 + (value desc, index asc) rank.
__global__ __launch_bounds__(256) void resolve_kernel(
    const float* __restrict__ conf, const float* __restrict__ warp,
    const float* __restrict__ gk, const int* __restrict__ st,
    const unsigned* __restrict__ ccount, const int* __restrict__ cidx,
    const unsigned* __restrict__ ckey, float* __restrict__ out) {
  int j = blockIdx.x;                // 40
  int b = j / 5, l = j % 5 + 1;
  int rowg = b * 6 + l;
  const float* confr = conf + (size_t)rowg * 4u * NPIX;
  const float* warpr = warp + (size_t)b * NPIX;
  __shared__ unsigned kk[CAND_CAP];  // 16 KB
  __shared__ int ii[CAND_CAP];       // 16 KB
  __shared__ double uvs[UCAP];       //  8 KB
  __shared__ int uid[UCAP];          //  4 KB
  __shared__ unsigned red[256];
  __shared__ double g[25];
  __shared__ unsigned s_kstar, s_ucnt;
  int tid = threadIdx.x;
  if (tid < 25) g[tid] = (double)gk[tid];
  if (tid == 0) { s_kstar = 0xFFFFFFFFu; s_ucnt = 0u; }
  int b1 = st[j * 2];
  int A1 = st[j * 2 + 1];
  int C = (int)min(ccount[j], (unsigned)CAND_CAP);
  unsigned binTop = ((unsigned)(b1 + 1)) << 8;   // keys >= binTop are in A1
  unsigned cntHi = 0;
  for (int i = tid; i < C; i += 256) {
    kk[i] = ckey[j * CAND_CAP + i];
    ii[i] = cidx[j * CAND_CAP + i];
    cntHi += kk[i] >= binTop ? 1u : 0u;
  }
  red[tid] = cntHi;
  __syncthreads();
  for (int sft = 128; sft > 0; sft >>= 1) {
    if (tid < sft) red[tid] += red[tid + sft];
    __syncthreads();
  }
  int T = KSEL - A1 + (int)red[0];   // winners among candidates
  __syncthreads();
  for (int i = tid; i < C; i += 256) {
    unsigned ki = kk[i];
    int gt = 0;
    for (int q = 0; q < C; ++q) gt += kk[q] > ki ? 1 : 0;
    if (gt < T) atomicMin(&s_kstar, ki);
  }
  __syncthreads();
  unsigned kstar = s_kstar;
  unsigned dc = 0;
  for (int i = tid; i < C; i += 256) {
    int d = (int)kk[i] - (int)kstar;
    if (d > KAPPA) {
      out[(size_t)rowg * NPIX + ii[i]] = 1.0f;
      dc++;
    } else if (d >= -KAPPA) {
      unsigned u = atomicAdd(&s_ucnt, 1u);
      if (u < UCAP) uid[u] = ii[i];
    }
  }
  red[tid] = dc;
  __syncthreads();
  for (int sft = 128; sft > 0; sft >>= 1) {
    if (tid < sft) red[tid] += red[tid + sft];
    __syncthreads();
  }
  int need = T - (int)red[0];
  int U = (int)min(s_ucnt, (unsigned)UCAP);
  for (int u = tid; u < U; u += 256) {
    int idx = uid[u];
    int y = idx >> 9, xx = idx & 511;
    double acc = 0.0;
#pragma unroll
    for (int dy = 0; dy < 5; ++dy)
#pragma unroll
      for (int dx = 0; dx < 5; ++dx)
        acc = fma(g[dy * 5 + dx], m_val(confr, warpr, y + dy - 2, xx + dx - 2), acc);
    uvs[u] = acc;
  }
  __syncthreads();
  for (int u = tid; u < U; u += 256) {
    double v = uvs[u];
    int id = uid[u];
    int r = 0;
    for (int q = 0; q < U; ++q) {
      double vq = uvs[q];
      r += (vq > v) || (vq == v && uid[q] < id) ? 1 : 0;
    }
    if (r < need) out[(size_t)rowg * NPIX + id] = 1.0f;
  }
  if (j == 0 && tid == 0) out[12582912] = 0.5f;  // rate == 0.5 exactly
}

extern "C" void kernel_launch(void* const* d_in, const int* in_sizes, int n_in,
                              void* d_out, int out_size, void* d_ws, size_t ws_size,
                              hipStream_t stream) {
  const float* conf = (const float*)d_in[0];
  const float* warp = (const float*)d_in[1];
  const float* gk   = (const float*)d_in[2];
  float* out = (float*)d_out;
  char* ws = (char*)d_ws;

  unsigned* keys = (unsigned*)(ws + OFF_KEY);
  unsigned* h1   = (unsigned*)(ws + OFF_H1);
  int*      st   = (int*)(ws + OFF_ST);
  unsigned* cc   = (unsigned*)(ws + OFF_CC);
  int*      ci   = (int*)(ws + OFF_CI);
  unsigned* ck   = (unsigned*)(ws + OFF_CK);

  // 4 kernels. No hipMemsetAsync.
  ego_fill_kernel<<<2048, 256, 0, stream>>>(out, h1);
  conv_kernel<<<NROWSEL * 16, 512, 0, stream>>>(conf, warp, gk, keys, h1);
  mask_gather_kernel<<<NROWSEL * 32, 256, 0, stream>>>(keys, h1, out, st, cc, ci, ck);
  resolve_kernel<<<NROWSEL, 256, 0, stream>>>(conf, warp, gk, st, cc, ci, ck, out);
}

// Round 15
// 131.044 us; speedup vs baseline: 1.8990x; 1.0117x over previous
//
#include <hip/hip_runtime.h>

// confidence_maps: (8,6,4,512,512) f32; warp_masks: (8,1,512,512) f32;
// gauss_kernel: (1,1,5,5) f32.
// Output: mask (48,1,512,512) f32 + rate scalar = 12,582,913 floats.
//
// Validated invariants (rounds 1-13, absmax 0.0 x13):
//  - rate == 0.5 exactly; ego rows (l==0) all-ones, excluded from rate.
//  - max_c(sigmoid) == sigmoid(max_c); separable gaussian factorization.
//  - 20-bit keys are exact integer surrogates: decided bits provably match
//    the f64 reference outside a +/-KAPPA=3 key band; band resolved by
//    exact-f64 (branchy m_val, 25-tap) rank with (value desc, index asc).
//  - R13 resolve: T = K - A1 + #(cand >= binTop); k* = T-th largest cand
//    key (int rank); f64-resolve only |key-k*|<=3.
//
// Round-14 (fix the gather atomic serialization; R13 profile: gather =
// 151.7us, VALUBusy 1.9%, 0.44 TB/s — C~850 same-address global atomicAdds
// per row at ~150ns each = ~130us):
//  - gather now aggregates candidates in an LDS stack (LDS atomics), then
//    ONE global atomicAdd per block reserves a range in cidx/ckey, then a
//    coalesced LDS->global copy. Same-address global atomics: 850 -> 32/row.
//  - conv512 / resolve / ego unchanged (R13-proven).

#define NROWSEL 40
#define NPIX    262144
#define KSEL    131072
#define CAND_CAP 4096
#define LCAP    2048
#define UCAP    1024
#define KAPPA   3

// ---- workspace layout (bytes) ----
#define OFF_KEY 0ull                   // 40*262144 u32 = 41,943,040
#define OFF_H1  41943040ull            // 40*4096 u32   =    655,360
#define OFF_ST  42598400ull            // 40*2 int      =        320
#define OFF_CC  42598720ull            // 40 u32        =        160
#define OFF_CI  42598880ull            // 40*4096 int   =    655,360
#define OFF_CK  43254240ull            // 40*4096 u32   =    655,360
#define META_U32 163960                // (H1+ST+CC)/4 = 655,840 B

// exact f64 m (identical formula rounds 1-13); used only in resolve.
__device__ __forceinline__ double m_val(const float* __restrict__ confr,
                                        const float* __restrict__ warpr,
                                        int gy, int gx) {
  if (gy < 0 || gy >= 512 || gx < 0 || gx >= 512) return 0.0;
  int off = gy * 512 + gx;
  float x0 = confr[off];
  float x1 = confr[NPIX + off];
  float x2 = confr[2 * NPIX + off];
  float x3 = confr[3 * NPIX + off];
  float mx = fmaxf(fmaxf(x0, x1), fmaxf(x2, x3));
  double s = 1.0 / (1.0 + exp(-(double)mx));
  return s * (double)warpr[off];
}

// K0: fill the 8 ego rows (l==0) with 1.0 AND zero selection metadata.
__global__ void ego_fill_kernel(float* __restrict__ out,
                                unsigned* __restrict__ meta) {
  int i = blockIdx.x * 256 + threadIdx.x;   // 524288 float4 units
  int b = i >> 16;
  int o4 = i & 65535;
  float4* p = (float4*)(out + (size_t)b * 6u * NPIX) + o4;
  *p = make_float4(1.f, 1.f, 1.f, 1.f);
  if (i < META_U32) meta[i] = 0u;
}

// K1: 512-wide row-streaming fused m + separable conv + 20-bit key store +
// 4096-bin histogram (k>>8). 512 thr/block, 32-row output segments.
__global__ __launch_bounds__(512) void conv_kernel(
    const float* __restrict__ conf, const float* __restrict__ warp,
    const float* __restrict__ gk, unsigned* __restrict__ keys,
    unsigned* __restrict__ hist1) {
  const int blk = blockIdx.x;        // 40 * 16
  const int j = blk >> 4;            // image 0..39
  const int y0 = (blk & 15) << 5;    // output rows y0..y0+31
  const int b = j / 5;
  const int l = j % 5 + 1;
  const float* confr = conf + (size_t)(b * 6 + l) * 4u * NPIX;
  const float* warpr = warp + (size_t)b * NPIX;

  __shared__ float mrow[8][512];     // 16384 B circular buffer
  __shared__ unsigned lh[4096];      // 16384 B histogram
  __shared__ float wr5[5], wc5[5];
  const int x = threadIdx.x;         // column
  if (x < 5) {
    wr5[x] = gk[10 + x];                 // c * a_dx  (middle row)
    wc5[x] = gk[x * 5 + 2] / gk[12];     // a_dy      (middle col / center)
  }
  for (int i = x; i < 4096; i += 512) lh[i] = 0u;

  auto mload = [&](int y) -> float {
    float v = 0.f;
    if (y >= 0 && y < 512) {
      int off = y * 512 + x;
      float a0 = confr[off];
      float a1 = confr[NPIX + off];
      float a2 = confr[2 * NPIX + off];
      float a3 = confr[3 * NPIX + off];
      float mx = fmaxf(fmaxf(a0, a1), fmaxf(a2, a3));
      v = warpr[off] / (1.0f + expf(-mx));
    }
    return v;
  };
  auto hconv = [&](int y) -> float {
    const float* r = mrow[y & 7];
    int xm2 = x >= 2 ? x - 2 : 0;
    int xm1 = x >= 1 ? x - 1 : 0;
    int xp1 = x <= 510 ? x + 1 : 511;
    int xp2 = x <= 509 ? x + 2 : 511;
    float v0 = x >= 2 ? r[xm2] : 0.f;
    float v1 = x >= 1 ? r[xm1] : 0.f;
    float v3 = x <= 510 ? r[xp1] : 0.f;
    float v4 = x <= 509 ? r[xp2] : 0.f;
    float a = v0 * wr5[0];
    a = fmaf(wr5[1], v1, a);
    a = fmaf(wr5[2], r[x], a);
    a = fmaf(wr5[3], v3, a);
    a = fmaf(wr5[4], v4, a);
    return a;
  };

  float mreg = mload(y0 - 2);
  for (int r = 0; r < 4; ++r) {
    mrow[(y0 - 2 + r) & 7][x] = mreg;
    mreg = mload(y0 - 1 + r);
  }
  __syncthreads();
  float h0 = hconv(y0 - 2);
  float h1 = hconv(y0 - 1);
  float h2 = hconv(y0);
  float h3 = hconv(y0 + 1);

  unsigned* keyrow = keys + (size_t)j * NPIX;
#pragma unroll 1
  for (int yy = y0; yy < y0 + 32; ++yy) {
    mrow[(yy + 2) & 7][x] = mreg;
    if (yy < y0 + 31) mreg = mload(yy + 3);
    __syncthreads();
    float h4 = hconv(yy + 2);
    float acc = h0 * wc5[0];
    acc = fmaf(wc5[1], h1, acc);
    acc = fmaf(wc5[2], h2, acc);
    acc = fmaf(wc5[3], h3, acc);
    acc = fmaf(wc5[4], h4, acc);
    unsigned k = (unsigned)fminf(fmaxf(acc * 1048576.0f, 0.0f), 1048575.0f);
    keyrow[yy * 512 + x] = k;
    atomicAdd(&lh[k >> 8], 1u);
    h0 = h1; h1 = h2; h2 = h3; h3 = h4;
  }
  __syncthreads();
  for (int i = x; i < 4096; i += 512)
    if (lh[i]) atomicAdd(&hist1[j * 4096 + i], lh[i]);
}

// K2: inline 4096-bin scan -> cutoff bin b1, A1; write decided mask bits;
// gather bin+band candidates via LDS stack + ONE global atomic per block.
__global__ __launch_bounds__(256) void mask_gather_kernel(
    const unsigned* __restrict__ keys, const unsigned* __restrict__ hist1,
    float* __restrict__ out, int* __restrict__ st,
    unsigned* __restrict__ ccount, int* __restrict__ cidx,
    unsigned* __restrict__ ckey) {
  int blk = blockIdx.x;              // 40 * 32
  int j = blk >> 5, seg = blk & 31;  // 8192 keys per segment
  int b = j / 5, l = j % 5 + 1;
  int rowg = b * 6 + l;
  __shared__ unsigned hs[4096];      // 16 KB
  __shared__ unsigned red[256];
  __shared__ int lidx[LCAP];         //  8 KB
  __shared__ unsigned lkey[LCAP];    //  8 KB
  __shared__ unsigned s_lcnt, s_base, s_n;
  __shared__ int s_b1;
  int tid = threadIdx.x;
  if (tid == 0) s_lcnt = 0u;
  for (int i = tid; i < 4096; i += 256) hs[i] = hist1[j * 4096 + i];
  __syncthreads();
  unsigned s = 0;
#pragma unroll 4
  for (int k = 0; k < 16; ++k) s += hs[tid * 16 + k];
  red[tid] = s;
  __syncthreads();
  if (tid == 0) {
    unsigned cum = 0; int b1 = 0; unsigned A1 = 0;
    for (int c = 255; c >= 0; --c) {
      if (cum + red[c] >= (unsigned)KSEL) {
        unsigned cc2 = cum;
        for (int k = 15; k >= 0; --k) {
          unsigned hv = hs[c * 16 + k];
          if (cc2 + hv >= (unsigned)KSEL) { b1 = c * 16 + k; A1 = cc2; break; }
          cc2 += hv;
        }
        break;
      }
      cum += red[c];
    }
    s_b1 = b1;
    if (seg == 0) { st[j * 2] = b1; st[j * 2 + 1] = (int)A1; }
  }
  __syncthreads();
  int lo_cut = (s_b1 << 8) - KAPPA;         // candidates: [lo_cut, hi_cut]
  int hi_cut = ((s_b1 + 1) << 8) + KAPPA;   // decided IN: key > hi_cut

  const uint4* kp = (const uint4*)(keys + (size_t)j * NPIX + seg * 8192);
  float4* o4 = (float4*)(out + (size_t)rowg * NPIX + seg * 8192);
#pragma unroll
  for (int it = 0; it < 8; ++it) {
    int q = tid + it * 256;
    uint4 k4 = kp[q];
    unsigned w[4] = {k4.x, k4.y, k4.z, k4.w};
    float4 mv;
    float* mf = (float*)&mv;
#pragma unroll
    for (int e = 0; e < 4; ++e) {
      int k = (int)w[e];
      mf[e] = k > hi_cut ? 1.f : 0.f;
      if (k >= lo_cut && k <= hi_cut) {
        unsigned sl = atomicAdd(&s_lcnt, 1u);       // LDS atomic (fast)
        if (sl < (unsigned)LCAP) {
          lidx[sl] = seg * 8192 + q * 4 + e;
          lkey[sl] = (unsigned)k;
        }
      }
    }
    o4[q] = mv;
  }
  __syncthreads();
  if (tid == 0) {
    unsigned n = min(s_lcnt, (unsigned)LCAP);
    s_n = n;
    s_base = n ? atomicAdd(&ccount[j], n) : 0u;     // ONE global atomic
  }
  __syncthreads();
  unsigned n = s_n, base = s_base;
  for (unsigned i = tid; i < n; i += 256) {
    unsigned d = base + i;
    if (d < (unsigned)CAND_CAP) {
      cidx[j * CAND_CAP + d] = lidx[i];
      ckey[j * CAND_CAP + d] = lkey[i];
    }
  }
}

// K3: in-kernel fine cutoff (R13-proven). T = #winners among candidates;
// k* = T-th largest candidate key; keys > k*+3 decided IN; |key-k*|<=3
// resolved by exact f64 + (value desc, index asc) rank.
__global__ __launch_bounds__(256) void resolve_kernel(
    const float* __restrict__ conf, const float* __restrict__ warp,
    const float* __restrict__ gk, const int* __restrict__ st,
    const unsigned* __restrict__ ccount, const int* __restrict__ cidx,
    const unsigned* __restrict__ ckey, float* __restrict__ out) {
  int j = blockIdx.x;                // 40
  int b = j / 5, l = j % 5 + 1;
  int rowg = b * 6 + l;
  const float* confr = conf + (size_t)rowg * 4u * NPIX;
  const float* warpr = warp + (size_t)b * NPIX;
  __shared__ unsigned kk[CAND_CAP];  // 16 KB
  __shared__ int ii[CAND_CAP];       // 16 KB
  __shared__ double uvs[UCAP];       //  8 KB
  __shared__ int uid[UCAP];          //  4 KB
  __shared__ unsigned red[256];
  __shared__ double g[25];
  __shared__ unsigned s_kstar, s_ucnt;
  int tid = threadIdx.x;
  if (tid < 25) g[tid] = (double)gk[tid];
  if (tid == 0) { s_kstar = 0xFFFFFFFFu; s_ucnt = 0u; }
  int b1 = st[j * 2];
  int A1 = st[j * 2 + 1];
  int C = (int)min(ccount[j], (unsigned)CAND_CAP);
  unsigned binTop = ((unsigned)(b1 + 1)) << 8;   // keys >= binTop are in A1
  unsigned cntHi = 0;
  for (int i = tid; i < C; i += 256) {
    kk[i] = ckey[j * CAND_CAP + i];
    ii[i] = cidx[j * CAND_CAP + i];
    cntHi += kk[i] >= binTop ? 1u : 0u;
  }
  red[tid] = cntHi;
  __syncthreads();
  for (int sft = 128; sft > 0; sft >>= 1) {
    if (tid < sft) red[tid] += red[tid + sft];
    __syncthreads();
  }
  int T = KSEL - A1 + (int)red[0];   // winners among candidates
  __syncthreads();
  for (int i = tid; i < C; i += 256) {
    unsigned ki = kk[i];
    int gt = 0;
    for (int q = 0; q < C; ++q) gt += kk[q] > ki ? 1 : 0;
    if (gt < T) atomicMin(&s_kstar, ki);
  }
  __syncthreads();
  unsigned kstar = s_kstar;
  unsigned dc = 0;
  for (int i = tid; i < C; i += 256) {
    int d = (int)kk[i] - (int)kstar;
    if (d > KAPPA) {
      out[(size_t)rowg * NPIX + ii[i]] = 1.0f;
      dc++;
    } else if (d >= -KAPPA) {
      unsigned u = atomicAdd(&s_ucnt, 1u);
      if (u < UCAP) uid[u] = ii[i];
    }
  }
  red[tid] = dc;
  __syncthreads();
  for (int sft = 128; sft > 0; sft >>= 1) {
    if (tid < sft) red[tid] += red[tid + sft];
    __syncthreads();
  }
  int need = T - (int)red[0];
  int U = (int)min(s_ucnt, (unsigned)UCAP);
  for (int u = tid; u < U; u += 256) {
    int idx = uid[u];
    int y = idx >> 9, xx = idx & 511;
    double acc = 0.0;
#pragma unroll
    for (int dy = 0; dy < 5; ++dy)
#pragma unroll
      for (int dx = 0; dx < 5; ++dx)
        acc = fma(g[dy * 5 + dx], m_val(confr, warpr, y + dy - 2, xx + dx - 2), acc);
    uvs[u] = acc;
  }
  __syncthreads();
  for (int u = tid; u < U; u += 256) {
    double v = uvs[u];
    int id = uid[u];
    int r = 0;
    for (int q = 0; q < U; ++q) {
      double vq = uvs[q];
      r += (vq > v) || (vq == v && uid[q] < id) ? 1 : 0;
    }
    if (r < need) out[(size_t)rowg * NPIX + id] = 1.0f;
  }
  if (j == 0 && tid == 0) out[12582912] = 0.5f;  // rate == 0.5 exactly
}

extern "C" void kernel_launch(void* const* d_in, const int* in_sizes, int n_in,
                              void* d_out, int out_size, void* d_ws, size_t ws_size,
                              hipStream_t stream) {
  const float* conf = (const float*)d_in[0];
  const float* warp = (const float*)d_in[1];
  const float* gk   = (const float*)d_in[2];
  float* out = (float*)d_out;
  char* ws = (char*)d_ws;

  unsigned* keys = (unsigned*)(ws + OFF_KEY);
  unsigned* h1   = (unsigned*)(ws + OFF_H1);
  int*      st   = (int*)(ws + OFF_ST);
  unsigned* cc   = (unsigned*)(ws + OFF_CC);
  int*      ci   = (int*)(ws + OFF_CI);
  unsigned* ck   = (unsigned*)(ws + OFF_CK);

  // 4 kernels. No hipMemsetAsync.
  ego_fill_kernel<<<2048, 256, 0, stream>>>(out, h1);
  conv_kernel<<<NROWSEL * 16, 512, 0, stream>>>(conf, warp, gk, keys, h1);
  mask_gather_kernel<<<NROWSEL * 32, 256, 0, stream>>>(keys, h1, out, st, cc, ci, ck);
  resolve_kernel<<<NROWSEL, 256, 0, stream>>>(conf, warp, gk, st, cc, ci, ck, out);
}

// Round 16
// 130.946 us; speedup vs baseline: 1.9004x; 1.0007x over previous
//
#include <hip/hip_runtime.h>

// confidence_maps: (8,6,4,512,512) f32; warp_masks: (8,1,512,512) f32;
// gauss_kernel: (1,1,5,5) f32.
// Output: mask (48,1,512,512) f32 + rate scalar = 12,582,913 floats.
//
// Validated invariants (rounds 1-13, absmax 0.0 x13):
//  - rate == 0.5 exactly; ego rows (l==0) all-ones, excluded from rate.
//  - max_c(sigmoid) == sigmoid(max_c); separable gaussian factorization.
//  - 20-bit keys are exact integer surrogates: decided bits provably match
//    the f64 reference outside a +/-KAPPA=3 key band; band resolved by
//    exact-f64 (branchy m_val, 25-tap) rank with (value desc, index asc).
//  - R13 resolve: T = K - A1 + #(cand >= binTop); k* = T-th largest cand
//    key (int rank); f64-resolve only |key-k*|<=3.
//
// Round-14 (fix the gather atomic serialization; R13 profile: gather =
// 151.7us, VALUBusy 1.9%, 0.44 TB/s — C~850 same-address global atomicAdds
// per row at ~150ns each = ~130us):
//  - gather now aggregates candidates in an LDS stack (LDS atomics), then
//    ONE global atomicAdd per block reserves a range in cidx/ckey, then a
//    coalesced LDS->global copy. Same-address global atomics: 850 -> 32/row.
//  - conv512 / resolve / ego unchanged (R13-proven).

#define NROWSEL 40
#define NPIX    262144
#define KSEL    131072
#define CAND_CAP 4096
#define LCAP    2048
#define UCAP    1024
#define KAPPA   3

// ---- workspace layout (bytes) ----
#define OFF_KEY 0ull                   // 40*262144 u32 = 41,943,040
#define OFF_H1  41943040ull            // 40*4096 u32   =    655,360
#define OFF_ST  42598400ull            // 40*2 int      =        320
#define OFF_CC  42598720ull            // 40 u32        =        160
#define OFF_CI  42598880ull            // 40*4096 int   =    655,360
#define OFF_CK  43254240ull            // 40*4096 u32   =    655,360
#define META_U32 163960                // (H1+ST+CC)/4 = 655,840 B

// exact f64 m (identical formula rounds 1-13); used only in resolve.
__device__ __forceinline__ double m_val(const float* __restrict__ confr,
                                        const float* __restrict__ warpr,
                                        int gy, int gx) {
  if (gy < 0 || gy >= 512 || gx < 0 || gx >= 512) return 0.0;
  int off = gy * 512 + gx;
  float x0 = confr[off];
  float x1 = confr[NPIX + off];
  float x2 = confr[2 * NPIX + off];
  float x3 = confr[3 * NPIX + off];
  float mx = fmaxf(fmaxf(x0, x1), fmaxf(x2, x3));
  double s = 1.0 / (1.0 + exp(-(double)mx));
  return s * (double)warpr[off];
}

// K0: fill the 8 ego rows (l==0) with 1.0 AND zero selection metadata.
__global__ void ego_fill_kernel(float* __restrict__ out,
                                unsigned* __restrict__ meta) {
  int i = blockIdx.x * 256 + threadIdx.x;   // 524288 float4 units
  int b = i >> 16;
  int o4 = i & 65535;
  float4* p = (float4*)(out + (size_t)b * 6u * NPIX) + o4;
  *p = make_float4(1.f, 1.f, 1.f, 1.f);
  if (i < META_U32) meta[i] = 0u;
}

// K1: 512-wide row-streaming fused m + separable conv + 20-bit key store +
// 4096-bin histogram (k>>8). 512 thr/block, 32-row output segments.
__global__ __launch_bounds__(512) void conv_kernel(
    const float* __restrict__ conf, const float* __restrict__ warp,
    const float* __restrict__ gk, unsigned* __restrict__ keys,
    unsigned* __restrict__ hist1) {
  const int blk = blockIdx.x;        // 40 * 16
  const int j = blk >> 4;            // image 0..39
  const int y0 = (blk & 15) << 5;    // output rows y0..y0+31
  const int b = j / 5;
  const int l = j % 5 + 1;
  const float* confr = conf + (size_t)(b * 6 + l) * 4u * NPIX;
  const float* warpr = warp + (size_t)b * NPIX;

  __shared__ float mrow[8][512];     // 16384 B circular buffer
  __shared__ unsigned lh[4096];      // 16384 B histogram
  __shared__ float wr5[5], wc5[5];
  const int x = threadIdx.x;         // column
  if (x < 5) {
    wr5[x] = gk[10 + x];                 // c * a_dx  (middle row)
    wc5[x] = gk[x * 5 + 2] / gk[12];     // a_dy      (middle col / center)
  }
  for (int i = x; i < 4096; i += 512) lh[i] = 0u;

  auto mload = [&](int y) -> float {
    float v = 0.f;
    if (y >= 0 && y < 512) {
      int off = y * 512 + x;
      float a0 = confr[off];
      float a1 = confr[NPIX + off];
      float a2 = confr[2 * NPIX + off];
      float a3 = confr[3 * NPIX + off];
      float mx = fmaxf(fmaxf(a0, a1), fmaxf(a2, a3));
      v = warpr[off] / (1.0f + expf(-mx));
    }
    return v;
  };
  auto hconv = [&](int y) -> float {
    const float* r = mrow[y & 7];
    int xm2 = x >= 2 ? x - 2 : 0;
    int xm1 = x >= 1 ? x - 1 : 0;
    int xp1 = x <= 510 ? x + 1 : 511;
    int xp2 = x <= 509 ? x + 2 : 511;
    float v0 = x >= 2 ? r[xm2] : 0.f;
    float v1 = x >= 1 ? r[xm1] : 0.f;
    float v3 = x <= 510 ? r[xp1] : 0.f;
    float v4 = x <= 509 ? r[xp2] : 0.f;
    float a = v0 * wr5[0];
    a = fmaf(wr5[1], v1, a);
    a = fmaf(wr5[2], r[x], a);
    a = fmaf(wr5[3], v3, a);
    a = fmaf(wr5[4], v4, a);
    return a;
  };

  float mreg = mload(y0 - 2);
  for (int r = 0; r < 4; ++r) {
    mrow[(y0 - 2 + r) & 7][x] = mreg;
    mreg = mload(y0 - 1 + r);
  }
  __syncthreads();
  float h0 = hconv(y0 - 2);
  float h1 = hconv(y0 - 1);
  float h2 = hconv(y0);
  float h3 = hconv(y0 + 1);

  unsigned* keyrow = keys + (size_t)j * NPIX;
#pragma unroll 1
  for (int yy = y0; yy < y0 + 32; ++yy) {
    mrow[(yy + 2) & 7][x] = mreg;
    if (yy < y0 + 31) mreg = mload(yy + 3);
    __syncthreads();
    float h4 = hconv(yy + 2);
    float acc = h0 * wc5[0];
    acc = fmaf(wc5[1], h1, acc);
    acc = fmaf(wc5[2], h2, acc);
    acc = fmaf(wc5[3], h3, acc);
    acc = fmaf(wc5[4], h4, acc);
    unsigned k = (unsigned)fminf(fmaxf(acc * 1048576.0f, 0.0f), 1048575.0f);
    keyrow[yy * 512 + x] = k;
    atomicAdd(&lh[k >> 8], 1u);
    h0 = h1; h1 = h2; h2 = h3; h3 = h4;
  }
  __syncthreads();
  for (int i = x; i < 4096; i += 512)
    if (lh[i]) atomicAdd(&hist1[j * 4096 + i], lh[i]);
}

// K2: inline 4096-bin scan -> cutoff bin b1, A1; write decided mask bits;
// gather bin+band candidates via LDS stack + ONE global atomic per block.
__global__ __launch_bounds__(256) void mask_gather_kernel(
    const unsigned* __restrict__ keys, const unsigned* __restrict__ hist1,
    float* __restrict__ out, int* __restrict__ st,
    unsigned* __restrict__ ccount, int* __restrict__ cidx,
    unsigned* __restrict__ ckey) {
  int blk = blockIdx.x;              // 40 * 32
  int j = blk >> 5, seg = blk & 31;  // 8192 keys per segment
  int b = j / 5, l = j % 5 + 1;
  int rowg = b * 6 + l;
  __shared__ unsigned hs[4096];      // 16 KB
  __shared__ unsigned red[256];
  __shared__ int lidx[LCAP];         //  8 KB
  __shared__ unsigned lkey[LCAP];    //  8 KB
  __shared__ unsigned s_lcnt, s_base, s_n;
  __shared__ int s_b1;
  int tid = threadIdx.x;
  if (tid == 0) s_lcnt = 0u;
  for (int i = tid; i < 4096; i += 256) hs[i] = hist1[j * 4096 + i];
  __syncthreads();
  unsigned s = 0;
#pragma unroll 4
  for (int k = 0; k < 16; ++k) s += hs[tid * 16 + k];
  red[tid] = s;
  __syncthreads();
  if (tid == 0) {
    unsigned cum = 0; int b1 = 0; unsigned A1 = 0;
    for (int c = 255; c >= 0; --c) {
      if (cum + red[c] >= (unsigned)KSEL) {
        unsigned cc2 = cum;
        for (int k = 15; k >= 0; --k) {
          unsigned hv = hs[c * 16 + k];
          if (cc2 + hv >= (unsigned)KSEL) { b1 = c * 16 + k; A1 = cc2; break; }
          cc2 += hv;
        }
        break;
      }
      cum += red[c];
    }
    s_b1 = b1;
    if (seg == 0) { st[j * 2] = b1; st[j * 2 + 1] = (int)A1; }
  }
  __syncthreads();
  int lo_cut = (s_b1 << 8) - KAPPA;         // candidates: [lo_cut, hi_cut]
  int hi_cut = ((s_b1 + 1) << 8) + KAPPA;   // decided IN: key > hi_cut

  const uint4* kp = (const uint4*)(keys + (size_t)j * NPIX + seg * 8192);
  float4* o4 = (float4*)(out + (size_t)rowg * NPIX + seg * 8192);
#pragma unroll
  for (int it = 0; it < 8; ++it) {
    int q = tid + it * 256;
    uint4 k4 = kp[q];
    unsigned w[4] = {k4.x, k4.y, k4.z, k4.w};
    float4 mv;
    float* mf = (float*)&mv;
#pragma unroll
    for (int e = 0; e < 4; ++e) {
      int k = (int)w[e];
      mf[e] = k > hi_cut ? 1.f : 0.f;
      if (k >= lo_cut && k <= hi_cut) {
        unsigned sl = atomicAdd(&s_lcnt, 1u);       // LDS atomic (fast)
        if (sl < (unsigned)LCAP) {
          lidx[sl] = seg * 8192 + q * 4 + e;
          lkey[sl] = (unsigned)k;
        }
      }
    }
    o4[q] = mv;
  }
  __syncthreads();
  if (tid == 0) {
    unsigned n = min(s_lcnt, (unsigned)LCAP);
    s_n = n;
    s_base = n ? atomicAdd(&ccount[j], n) : 0u;     // ONE global atomic
  }
  __syncthreads();
  unsigned n = s_n, base = s_base;
  for (unsigned i = tid; i < n; i += 256) {
    unsigned d = base + i;
    if (d < (unsigned)CAND_CAP) {
      cidx[j * CAND_CAP + d] = lidx[i];
      ckey[j * CAND_CAP + d] = lkey[i];
    }
  }
}

// K3: in-kernel fine cutoff (R13-proven). T = #winners among candidates;
// k* = T-th largest candidate key; keys > k*+3 decided IN; |key-k*|<=3
// resolved by exact f64 + (value desc, index asc) rank.
__global__ __launch_bounds__(256) void resolve_kernel(
    const float* __restrict__ conf, const float* __restrict__ warp,
    const float* __restrict__ gk, const int* __restrict__ st,
    const unsigned* __restrict__ ccount, const int* __restrict__ cidx,
    const unsigned* __restrict__ ckey, float* __restrict__ out) {
  int j = blockIdx.x;                // 40
  int b = j / 5, l = j % 5 + 1;
  int rowg = b * 6 + l;
  const float* confr = conf + (size_t)rowg * 4u * NPIX;
  const float* warpr = warp + (size_t)b * NPIX;
  __shared__ unsigned kk[CAND_CAP];  // 16 KB
  __shared__ int ii[CAND_CAP];       // 16 KB
  __shared__ double uvs[UCAP];       //  8 KB
  __shared__ int uid[UCAP];          //  4 KB
  __shared__ unsigned red[256];
  __shared__ double g[25];
  __shared__ unsigned s_kstar, s_ucnt;
  int tid = threadIdx.x;
  if (tid < 25) g[tid] = (double)gk[tid];
  if (tid == 0) { s_kstar = 0xFFFFFFFFu; s_ucnt = 0u; }
  int b1 = st[j * 2];
  int A1 = st[j * 2 + 1];
  int C = (int)min(ccount[j], (unsigned)CAND_CAP);
  unsigned binTop = ((unsigned)(b1 + 1)) << 8;   // keys >= binTop are in A1
  unsigned cntHi = 0;
  for (int i = tid; i < C; i += 256) {
    kk[i] = ckey[j * CAND_CAP + i];
    ii[i] = cidx[j * CAND_CAP + i];
    cntHi += kk[i] >= binTop ? 1u : 0u;
  }
  red[tid] = cntHi;
  __syncthreads();
  for (int sft = 128; sft > 0; sft >>= 1) {
    if (tid < sft) red[tid] += red[tid + sft];
    __syncthreads();
  }
  int T = KSEL - A1 + (int)red[0];   // winners among candidates
  __syncthreads();
  for (int i = tid; i < C; i += 256) {
    unsigned ki = kk[i];
    int gt = 0;
    for (int q = 0; q < C; ++q) gt += kk[q] > ki ? 1 : 0;
    if (gt < T) atomicMin(&s_kstar, ki);
  }
  __syncthreads();
  unsigned kstar = s_kstar;
  unsigned dc = 0;
  for (int i = tid; i < C; i += 256) {
    int d = (int)kk[i] - (int)kstar;
    if (d > KAPPA) {
      out[(size_t)rowg * NPIX + ii[i]] = 1.0f;
      dc++;
    } else if (d >= -KAPPA) {
      unsigned u = atomicAdd(&s_ucnt, 1u);
      if (u < UCAP) uid[u] = ii[i];
    }
  }
  red[tid] = dc;
  __syncthreads();
  for (int sft = 128; sft > 0; sft >>= 1) {
    if (tid < sft) red[tid] += red[tid + sft];
    __syncthreads();
  }
  int need = T - (int)red[0];
  int U = (int)min(s_ucnt, (unsigned)UCAP);
  for (int u = tid; u < U; u += 256) {
    int idx = uid[u];
    int y = idx >> 9, xx = idx & 511;
    double acc = 0.0;
#pragma unroll
    for (int dy = 0; dy < 5; ++dy)
#pragma unroll
      for (int dx = 0; dx < 5; ++dx)
        acc = fma(g[dy * 5 + dx], m_val(confr, warpr, y + dy - 2, xx + dx - 2), acc);
    uvs[u] = acc;
  }
  __syncthreads();
  for (int u = tid; u < U; u += 256) {
    double v = uvs[u];
    int id = uid[u];
    int r = 0;
    for (int q = 0; q < U; ++q) {
      double vq = uvs[q];
      r += (vq > v) || (vq == v && uid[q] < id) ? 1 : 0;
    }
    if (r < need) out[(size_t)rowg * NPIX + id] = 1.0f;
  }
  if (j == 0 && tid == 0) out[12582912] = 0.5f;  // rate == 0.5 exactly
}

extern "C" void kernel_launch(void* const* d_in, const int* in_sizes, int n_in,
                              void* d_out, int out_size, void* d_ws, size_t ws_size,
                              hipStream_t stream) {
  const float* conf = (const float*)d_in[0];
  const float* warp = (const float*)d_in[1];
  const float* gk   = (const float*)d_in[2];
  float* out = (float*)d_out;
  char* ws = (char*)d_ws;

  unsigned* keys = (unsigned*)(ws + OFF_KEY);
  unsigned* h1   = (unsigned*)(ws + OFF_H1);
  int*      st   = (int*)(ws + OFF_ST);
  unsigned* cc   = (unsigned*)(ws + OFF_CC);
  int*      ci   = (int*)(ws + OFF_CI);
  unsigned* ck   = (unsigned*)(ws + OFF_CK);

  // 4 kernels. No hipMemsetAsync.
  ego_fill_kernel<<<2048, 256, 0, stream>>>(out, h1);
  conv_kernel<<<NROWSEL * 16, 512, 0, stream>>>(conf, warp, gk, keys, h1);
  mask_gather_kernel<<<NROWSEL * 32, 256, 0, stream>>>(keys, h1, out, st, cc, ci, ck);
  resolve_kernel<<<NROWSEL, 256, 0, stream>>>(conf, warp, gk, st, cc, ci, ck, out);
}